// Round 2
// baseline (126.411 us; speedup 1.0000x reference)
//
#include <hip/hip_runtime.h>
#include <math.h>

#define Bn 32
#define Cn 512
#define Hn 56
#define Wn 56
#define HW (Hn*Wn)        // 3136
#define NPLANE (Bn*Cn)    // 16384

// ---------------------------------------------------------------------------
// Kernel A: per-(b,c) multi-scale pooling + conv chain -> scalar s0[bc]
// One block per (b,c). Loads the 12.5KB plane coalesced into LDS, computes
// the 16 y4 means (14x14 block means), derives y2/y1 exactly (equal-weight
// averages of y4 cells), then the two tiny convs in closed form.
// ---------------------------------------------------------------------------
__global__ __launch_bounds__(256) void pool_conv_kernel(
    const float* __restrict__ x,
    const float* __restrict__ w1,   // [3][3][3] (ic,ky,kx)
    const float* __restrict__ w2,   // [3][3]
    float* __restrict__ s0)         // [NPLANE]
{
    __shared__ float plane[HW];     // 12544 B
    __shared__ float rs[Hn * 4];    // row-segment sums
    __shared__ float y4[16];

    const int bc = blockIdx.x;
    const int t  = threadIdx.x;
    const float* src = x + (size_t)bc * HW;

    // coalesced load: 784 float4 per plane
    for (int f = t; f < HW / 4; f += 256)
        ((float4*)plane)[f] = ((const float4*)src)[f];
    __syncthreads();

    // 224 threads: thread (h, j) sums plane[h, j*14 .. j*14+13]
    if (t < Hn * 4) {
        const int h = t >> 2, j = t & 3;
        const float* row = plane + h * Wn + j * 14;
        float s = 0.f;
        #pragma unroll
        for (int e = 0; e < 14; ++e) s += row[e];
        rs[h * 4 + j] = s;
    }
    __syncthreads();

    // 16 threads: y4[i][j] = mean over 14 rows of segment sums
    if (t < 16) {
        const int i = t >> 2, j = t & 3;
        float s = 0.f;
        #pragma unroll
        for (int r = 0; r < 14; ++r) s += rs[(i * 14 + r) * 4 + j];
        y4[i * 4 + j] = s * (1.0f / 196.0f);
    }
    __syncthreads();

    if (t == 0) {
        // y2[p][q] = mean of quadrant = avg of 4 y4 cells (equal weights)
        float y2[2][2];
        #pragma unroll
        for (int p = 0; p < 2; ++p)
            #pragma unroll
            for (int q = 0; q < 2; ++q)
                y2[p][q] = 0.25f * (y4[(2*p)*4 + 2*q]   + y4[(2*p)*4 + 2*q+1]
                                  + y4[(2*p+1)*4 + 2*q] + y4[(2*p+1)*4 + 2*q+1]);
        const float y1 = 0.25f * (y2[0][0] + y2[0][1] + y2[1][0] + y2[1][1]);

        // conv1: t-channels [y1(const), y2-upsampled, y4], 4x4 -> 2x2 VALID
        float z[2][2];
        #pragma unroll
        for (int oy = 0; oy < 2; ++oy)
            #pragma unroll
            for (int ox = 0; ox < 2; ++ox) {
                float acc = 0.f;
                #pragma unroll
                for (int ky = 0; ky < 3; ++ky)
                    #pragma unroll
                    for (int kx = 0; kx < 3; ++kx) {
                        const int yy = oy + ky, xx = ox + kx;
                        acc += y1                  * w1[0*9 + ky*3 + kx];
                        acc += y2[yy >> 1][xx >> 1] * w1[1*9 + ky*3 + kx];
                        acc += y4[yy*4 + xx]        * w1[2*9 + ky*3 + kx];
                    }
                z[oy][ox] = acc;
            }

        // conv2: pad 1, stride 3, k=3 on 2x2 -> single output
        const float out = z[0][0] * w2[1*3+1] + z[0][1] * w2[1*3+2]
                        + z[1][0] * w2[2*3+1] + z[1][1] * w2[2*3+2];
        s0[bc] = out;
    }
}

// ---------------------------------------------------------------------------
// Kernel B: per-batch FC1(relu) + FC2 + sigmoid.  32 blocks x 256 threads.
// ---------------------------------------------------------------------------
__global__ __launch_bounds__(256) void fc_kernel(
    const float* __restrict__ s0,    // [Bn*Cn]
    const float* __restrict__ fc1,   // [32][512]
    const float* __restrict__ fc2,   // [512][32]
    float* __restrict__ s)           // [Bn*Cn]
{
    __shared__ float sv[Cn];
    __shared__ float hv[32];
    const int b = blockIdx.x;
    const int t = threadIdx.x;

    for (int c = t; c < Cn; c += 256) sv[c] = s0[b * Cn + c];
    __syncthreads();

    // h[r] = relu(sum_c sv[c] * fc1[r][c]); 8 lanes per r
    {
        const int r = t >> 3, lane8 = t & 7;
        float acc = 0.f;
        for (int c = lane8; c < Cn; c += 8) acc += sv[c] * fc1[r * Cn + c];
        acc += __shfl_xor(acc, 1);
        acc += __shfl_xor(acc, 2);
        acc += __shfl_xor(acc, 4);
        if (lane8 == 0) hv[r] = fmaxf(acc, 0.f);
    }
    __syncthreads();

    // s[c] = sigmoid(sum_r hv[r] * fc2[c][r])
    for (int c = t; c < Cn; c += 256) {
        float acc = 0.f;
        #pragma unroll
        for (int r = 0; r < 32; ++r) acc += hv[r] * fc2[c * 32 + r];
        s[b * Cn + c] = 1.0f / (1.0f + expf(-acc));
    }
}

// ---------------------------------------------------------------------------
// Kernel C: out = x * s[bc], vectorized float4, grid-stride
// ---------------------------------------------------------------------------
__global__ __launch_bounds__(256) void scale_kernel(
    const float* __restrict__ x,
    const float* __restrict__ s,     // [Bn*Cn]
    float* __restrict__ out)
{
    const int n4 = NPLANE * HW / 4;          // 12845056 float4s
    const int stride = gridDim.x * blockDim.x;
    for (int i = blockIdx.x * blockDim.x + threadIdx.x; i < n4; i += stride) {
        float4 v = ((const float4*)x)[i];
        const float sc = s[i / (HW / 4)];    // 784 float4 per plane
        v.x *= sc; v.y *= sc; v.z *= sc; v.w *= sc;
        ((float4*)out)[i] = v;
    }
}

extern "C" void kernel_launch(void* const* d_in, const int* in_sizes, int n_in,
                              void* d_out, int out_size, void* d_ws, size_t ws_size,
                              hipStream_t stream) {
    const float* x   = (const float*)d_in[0];
    const float* w1  = (const float*)d_in[1];
    const float* w2  = (const float*)d_in[2];
    const float* fc1 = (const float*)d_in[3];
    const float* fc2 = (const float*)d_in[4];
    float* out = (float*)d_out;

    float* s0 = (float*)d_ws;          // [16384]
    float* s  = s0 + NPLANE;           // [16384]

    pool_conv_kernel<<<NPLANE, 256, 0, stream>>>(x, w1, w2, s0);
    fc_kernel<<<Bn, 256, 0, stream>>>(s0, fc1, fc2, s);
    scale_kernel<<<2048, 256, 0, stream>>>(x, s, out);
}

// Round 4
// 108.067 us; speedup vs baseline: 1.1698x; 1.1698x over previous
//
#include <hip/hip_runtime.h>
#include <math.h>

#define Bn 32
#define Cn 512
#define Hn 56
#define Wn 56
#define HW (Hn*Wn)           // 3136
#define NPLANE (Bn*Cn)       // 16384
#define F4_PER_PLANE (HW/4)  // 784

typedef float f4 __attribute__((ext_vector_type(4)));

// ---------------------------------------------------------------------------
// Kernel A: per-(b,c) multi-scale pooling + conv chain -> scalar s0[bc]
// One block per (b,c). Loads the 12.5KB plane coalesced into LDS, computes
// the 16 y4 means (14x14 block means), derives y2/y1 exactly (equal-weight
// averages of y4 cells), then the two tiny convs in closed form.
// ---------------------------------------------------------------------------
__global__ __launch_bounds__(256) void pool_conv_kernel(
    const float* __restrict__ x,
    const float* __restrict__ w1,   // [3][3][3] (ic,ky,kx)
    const float* __restrict__ w2,   // [3][3]
    float* __restrict__ s0)         // [NPLANE]
{
    __shared__ float plane[HW];     // 12544 B
    __shared__ float rs[Hn * 4];    // row-segment sums
    __shared__ float y4[16];

    const int bc = blockIdx.x;
    const int t  = threadIdx.x;
    const float* src = x + (size_t)bc * HW;

    // coalesced load: 784 float4 per plane (x is 16B-aligned per plane)
    for (int f = t; f < F4_PER_PLANE; f += 256)
        ((f4*)plane)[f] = ((const f4*)src)[f];
    __syncthreads();

    // 224 threads: thread (h, j) sums plane[h, j*14 .. j*14+13]
    if (t < Hn * 4) {
        const int h = t >> 2, j = t & 3;
        const float* row = plane + h * Wn + j * 14;
        float s = 0.f;
        #pragma unroll
        for (int e = 0; e < 14; ++e) s += row[e];
        rs[h * 4 + j] = s;
    }
    __syncthreads();

    // 16 threads: y4[i][j] = mean over 14 rows of segment sums
    if (t < 16) {
        const int i = t >> 2, j = t & 3;
        float s = 0.f;
        #pragma unroll
        for (int r = 0; r < 14; ++r) s += rs[(i * 14 + r) * 4 + j];
        y4[i * 4 + j] = s * (1.0f / 196.0f);
    }
    __syncthreads();

    if (t == 0) {
        // y2[p][q] = mean of quadrant = avg of 4 y4 cells (equal weights)
        float y2[2][2];
        #pragma unroll
        for (int p = 0; p < 2; ++p)
            #pragma unroll
            for (int q = 0; q < 2; ++q)
                y2[p][q] = 0.25f * (y4[(2*p)*4 + 2*q]   + y4[(2*p)*4 + 2*q+1]
                                  + y4[(2*p+1)*4 + 2*q] + y4[(2*p+1)*4 + 2*q+1]);
        const float y1 = 0.25f * (y2[0][0] + y2[0][1] + y2[1][0] + y2[1][1]);

        // conv1: channels [y1(const), y2-upsampled, y4], 4x4 -> 2x2 VALID
        float z[2][2];
        #pragma unroll
        for (int oy = 0; oy < 2; ++oy)
            #pragma unroll
            for (int ox = 0; ox < 2; ++ox) {
                float acc = 0.f;
                #pragma unroll
                for (int ky = 0; ky < 3; ++ky)
                    #pragma unroll
                    for (int kx = 0; kx < 3; ++kx) {
                        const int yy = oy + ky, xx = ox + kx;
                        acc += y1                   * w1[0*9 + ky*3 + kx];
                        acc += y2[yy >> 1][xx >> 1] * w1[1*9 + ky*3 + kx];
                        acc += y4[yy*4 + xx]        * w1[2*9 + ky*3 + kx];
                    }
                z[oy][ox] = acc;
            }

        // conv2: pad 1, stride 3, k=3 on 2x2 -> single output
        s0[bc] = z[0][0] * w2[1*3+1] + z[0][1] * w2[1*3+2]
               + z[1][0] * w2[2*3+1] + z[1][1] * w2[2*3+2];
    }
}

// ---------------------------------------------------------------------------
// Kernel B (fused FC + scale): grid = Bn*64 blocks. Block (b, kk) recomputes
// the tiny per-batch FC (33 KFLOP, redundant across the batch's 64 blocks —
// negligible) and scales its 8 planes. out is written with NONTEMPORAL
// stores so the 205 MB of writes don't evict x from the 256 MB L3 —
// the x re-read should then be an L3 hit.
// ---------------------------------------------------------------------------
__global__ __launch_bounds__(256) void fc_scale_kernel(
    const float* __restrict__ x,
    const float* __restrict__ s0,    // [Bn*Cn]
    const float* __restrict__ fc1,   // [32][512]
    const float* __restrict__ fc2,   // [512][32]
    float* __restrict__ out)
{
    __shared__ float sv[Cn];
    __shared__ float hv[32];
    __shared__ float scl[8];

    const int b  = blockIdx.x >> 6;        // batch
    const int kk = blockIdx.x & 63;        // 8-plane group within batch
    const int t  = threadIdx.x;

    for (int c = t; c < Cn; c += 256) sv[c] = s0[b * Cn + c];
    __syncthreads();

    // h[r] = relu(sum_c sv[c] * fc1[r][c]); 8 lanes per r (within one wave)
    {
        const int r = t >> 3, lane8 = t & 7;
        float acc = 0.f;
        for (int c = lane8; c < Cn; c += 8) acc += sv[c] * fc1[r * Cn + c];
        acc += __shfl_xor(acc, 1);
        acc += __shfl_xor(acc, 2);
        acc += __shfl_xor(acc, 4);
        if (lane8 == 0) hv[r] = fmaxf(acc, 0.f);
    }
    __syncthreads();

    // scl[p] = sigmoid(hv . fc2[kk*8+p]) for this block's 8 channels
    if (t < 8) {
        const int c = kk * 8 + t;
        float acc = 0.f;
        #pragma unroll
        for (int r = 0; r < 32; ++r) acc += hv[r] * fc2[c * 32 + r];
        scl[t] = 1.0f / (1.0f + expf(-acc));
    }
    __syncthreads();

    // scale 8 planes, nontemporal stores
    #pragma unroll
    for (int p = 0; p < 8; ++p) {
        const int plane = b * Cn + kk * 8 + p;
        const float sc = scl[p];
        const f4* px = (const f4*)x + (size_t)plane * F4_PER_PLANE;
        f4* po = (f4*)out + (size_t)plane * F4_PER_PLANE;
        for (int f = t; f < F4_PER_PLANE; f += 256) {
            f4 v = px[f];
            v *= sc;
            __builtin_nontemporal_store(v, po + f);
        }
    }
}

extern "C" void kernel_launch(void* const* d_in, const int* in_sizes, int n_in,
                              void* d_out, int out_size, void* d_ws, size_t ws_size,
                              hipStream_t stream) {
    const float* x   = (const float*)d_in[0];
    const float* w1  = (const float*)d_in[1];
    const float* w2  = (const float*)d_in[2];
    const float* fc1 = (const float*)d_in[3];
    const float* fc2 = (const float*)d_in[4];
    float* out = (float*)d_out;

    float* s0 = (float*)d_ws;          // [16384]

    pool_conv_kernel<<<NPLANE, 256, 0, stream>>>(x, w1, w2, s0);
    fc_scale_kernel<<<Bn * 64, 256, 0, stream>>>(x, s0, fc1, fc2, out);
}

// Round 5
// 107.697 us; speedup vs baseline: 1.1738x; 1.0034x over previous
//
#include <hip/hip_runtime.h>
#include <math.h>

#define Bn 32
#define Cn 512
#define Hn 56
#define Wn 56
#define HW (Hn*Wn)           // 3136
#define NPLANE (Bn*Cn)       // 16384
#define F4_PER_PLANE (HW/4)  // 784

typedef float f4 __attribute__((ext_vector_type(4)));

// ---------------------------------------------------------------------------
// Kernel A: per-(b,c) multi-scale pooling + conv chain -> scalar s0[bc]
// One block per (b,c). Loads the 12.5KB plane coalesced into LDS, computes
// the 16 y4 means (14x14 block means), derives y2/y1 exactly (equal-weight
// averages of y4 cells), then the two tiny convs in closed form.
// ---------------------------------------------------------------------------
__global__ __launch_bounds__(256) void pool_conv_kernel(
    const float* __restrict__ x,
    const float* __restrict__ w1,   // [3][3][3] (ic,ky,kx)
    const float* __restrict__ w2,   // [3][3]
    float* __restrict__ s0)         // [NPLANE]
{
    __shared__ float plane[HW];     // 12544 B
    __shared__ float rs[Hn * 4];    // row-segment sums
    __shared__ float y4[16];

    const int bc = blockIdx.x;
    const int t  = threadIdx.x;
    const float* src = x + (size_t)bc * HW;

    // coalesced load: 784 float4 per plane (x is 16B-aligned per plane)
    for (int f = t; f < F4_PER_PLANE; f += 256)
        ((f4*)plane)[f] = ((const f4*)src)[f];
    __syncthreads();

    // 224 threads: thread (h, j) sums plane[h, j*14 .. j*14+13]
    if (t < Hn * 4) {
        const int h = t >> 2, j = t & 3;
        const float* row = plane + h * Wn + j * 14;
        float s = 0.f;
        #pragma unroll
        for (int e = 0; e < 14; ++e) s += row[e];
        rs[h * 4 + j] = s;
    }
    __syncthreads();

    // 16 threads: y4[i][j] = mean over 14 rows of segment sums
    if (t < 16) {
        const int i = t >> 2, j = t & 3;
        float s = 0.f;
        #pragma unroll
        for (int r = 0; r < 14; ++r) s += rs[(i * 14 + r) * 4 + j];
        y4[i * 4 + j] = s * (1.0f / 196.0f);
    }
    __syncthreads();

    if (t == 0) {
        // y2[p][q] = mean of quadrant = avg of 4 y4 cells (equal weights)
        float y2[2][2];
        #pragma unroll
        for (int p = 0; p < 2; ++p)
            #pragma unroll
            for (int q = 0; q < 2; ++q)
                y2[p][q] = 0.25f * (y4[(2*p)*4 + 2*q]   + y4[(2*p)*4 + 2*q+1]
                                  + y4[(2*p+1)*4 + 2*q] + y4[(2*p+1)*4 + 2*q+1]);
        const float y1 = 0.25f * (y2[0][0] + y2[0][1] + y2[1][0] + y2[1][1]);

        // conv1: channels [y1(const), y2-upsampled, y4], 4x4 -> 2x2 VALID
        float z[2][2];
        #pragma unroll
        for (int oy = 0; oy < 2; ++oy)
            #pragma unroll
            for (int ox = 0; ox < 2; ++ox) {
                float acc = 0.f;
                #pragma unroll
                for (int ky = 0; ky < 3; ++ky)
                    #pragma unroll
                    for (int kx = 0; kx < 3; ++kx) {
                        const int yy = oy + ky, xx = ox + kx;
                        acc += y1                   * w1[0*9 + ky*3 + kx];
                        acc += y2[yy >> 1][xx >> 1] * w1[1*9 + ky*3 + kx];
                        acc += y4[yy*4 + xx]        * w1[2*9 + ky*3 + kx];
                    }
                z[oy][ox] = acc;
            }

        // conv2: pad 1, stride 3, k=3 on 2x2 -> single output
        s0[bc] = z[0][0] * w2[1*3+1] + z[0][1] * w2[1*3+2]
               + z[1][0] * w2[2*3+1] + z[1][1] * w2[2*3+2];
    }
}

// ---------------------------------------------------------------------------
// Kernel B (fused FC + scale): grid = Bn*64 blocks. Block handles 8 planes,
// recomputing the tiny per-batch FC (33 KFLOP, redundant — negligible).
// REVERSE plane order: phase 1 cached planes ascending, so the L3 holds the
// highest-index ~256MB worth; walking phase 2 descending turns the re-read
// into L3 hits instead of LRU sequential-thrash misses. out uses NONTEMPORAL
// stores so the 205 MB of writes don't evict x from the L3 during the walk.
// ---------------------------------------------------------------------------
__global__ __launch_bounds__(256) void fc_scale_kernel(
    const float* __restrict__ x,
    const float* __restrict__ s0,    // [Bn*Cn]
    const float* __restrict__ fc1,   // [32][512]
    const float* __restrict__ fc2,   // [512][32]
    float* __restrict__ out)
{
    __shared__ float sv[Cn];
    __shared__ float hv[32];
    __shared__ float scl[8];

    const int rbid = (Bn * 64 - 1) - blockIdx.x;   // reversed dispatch order
    const int b  = rbid >> 6;        // batch
    const int kk = rbid & 63;        // 8-plane group within batch
    const int t  = threadIdx.x;

    for (int c = t; c < Cn; c += 256) sv[c] = s0[b * Cn + c];
    __syncthreads();

    // h[r] = relu(sum_c sv[c] * fc1[r][c]); 8 lanes per r (within one wave)
    {
        const int r = t >> 3, lane8 = t & 7;
        float acc = 0.f;
        for (int c = lane8; c < Cn; c += 8) acc += sv[c] * fc1[r * Cn + c];
        acc += __shfl_xor(acc, 1);
        acc += __shfl_xor(acc, 2);
        acc += __shfl_xor(acc, 4);
        if (lane8 == 0) hv[r] = fmaxf(acc, 0.f);
    }
    __syncthreads();

    // scl[p] = sigmoid(hv . fc2[kk*8+p]) for this block's 8 channels
    if (t < 8) {
        const int c = kk * 8 + t;
        float acc = 0.f;
        #pragma unroll
        for (int r = 0; r < 32; ++r) acc += hv[r] * fc2[c * 32 + r];
        scl[t] = 1.0f / (1.0f + expf(-acc));
    }
    __syncthreads();

    // scale 8 planes (descending, to match the L3 resident tail), nt stores
    #pragma unroll
    for (int p = 7; p >= 0; --p) {
        const int plane = b * Cn + kk * 8 + p;
        const float sc = scl[p];
        const f4* px = (const f4*)x + (size_t)plane * F4_PER_PLANE;
        f4* po = (f4*)out + (size_t)plane * F4_PER_PLANE;
        for (int f = t; f < F4_PER_PLANE; f += 256) {
            f4 v = px[f];
            v *= sc;
            __builtin_nontemporal_store(v, po + f);
        }
    }
}

extern "C" void kernel_launch(void* const* d_in, const int* in_sizes, int n_in,
                              void* d_out, int out_size, void* d_ws, size_t ws_size,
                              hipStream_t stream) {
    const float* x   = (const float*)d_in[0];
    const float* w1  = (const float*)d_in[1];
    const float* w2  = (const float*)d_in[2];
    const float* fc1 = (const float*)d_in[3];
    const float* fc2 = (const float*)d_in[4];
    float* out = (float*)d_out;

    float* s0 = (float*)d_ws;          // [16384]

    pool_conv_kernel<<<NPLANE, 256, 0, stream>>>(x, w1, w2, s0);
    fc_scale_kernel<<<Bn * 64, 256, 0, stream>>>(x, s0, fc1, fc2, out);
}